// Round 6
// baseline (381.579 us; speedup 1.0000x reference)
//
#include <hip/hip_runtime.h>
#include <stdint.h>

#define NNODES 32768
#define NREL 10
#define NBASES 4
#define DIM 256
#define NEDGE 524288
#define KW 1280                 /* 4*256 basis + 256 root */
#define KBASE 1024              /* z width */

typedef __attribute__((ext_vector_type(8))) short bf16x8;
typedef __attribute__((ext_vector_type(4))) float f32x4;

__device__ __forceinline__ float bf2f(unsigned short u){
  union { unsigned int i; float f; } v; v.i = ((unsigned int)u) << 16; return v.f;
}
__device__ __forceinline__ unsigned short f2bf(float f){
  union { float f; unsigned int i; } v; v.f = f;
  unsigned int x = v.i;
  unsigned int r = (x + 0x7FFFu + ((x >> 16) & 1u)) >> 16;
  return (unsigned short)r;
}
__device__ __forceinline__ void gll16(const void* g, void* l){
  __builtin_amdgcn_global_load_lds((const __attribute__((address_space(1))) void*)g,
                                   (__attribute__((address_space(3))) void*)l, 16, 0, 0);
}

// ----------------------------------------------------- fp32 -> bf16 convert
__global__ __launch_bounds__(256) void conv_kernel(const float* __restrict__ in,
                                                   unsigned short* __restrict__ out)
{
  int i = blockIdx.x * 256 + threadIdx.x;
  float4 v = ((const float4*)in)[i];
  ushort4 o; o.x = f2bf(v.x); o.y = f2bf(v.y); o.z = f2bf(v.z); o.w = f2bf(v.w);
  ((ushort4*)out)[i] = o;
}

// ------------------------------------------------ histogram: per-(r,d) only
__global__ void hist_kernel(const int* __restrict__ ec, const int* __restrict__ rel,
                            int* __restrict__ cnt_rd)
{
  int e = blockIdx.x * 256 + threadIdx.x;
  int d = ec[NEDGE + e];
  int r = rel[e];
  atomicAdd(&cnt_rd[(r << 15) + d], 1);
}

// ---------------- 3-phase exclusive scan over deg (deg = sum_r cnt_rd[r,d])
__global__ __launch_bounds__(1024) void scan1(const int* __restrict__ cnt_rd,
                                              int* __restrict__ offs, int* __restrict__ blksum)
{
  __shared__ int sh[1024];
  int tid = threadIdx.x; int gid = blockIdx.x * 1024 + tid;
  int v = 0;
#pragma unroll
  for (int r = 0; r < NREL; r++) v += cnt_rd[(r << 15) + gid];
  sh[tid] = v; __syncthreads();
  for (int off = 1; off < 1024; off <<= 1){
    int t = (tid >= off) ? sh[tid - off] : 0;
    __syncthreads(); sh[tid] += t; __syncthreads();
  }
  offs[gid] = sh[tid] - v;
  if (tid == 1023) blksum[blockIdx.x] = sh[1023];
}
__global__ __launch_bounds__(64) void scan2(int* __restrict__ blksum)
{
  __shared__ int sh[64];
  int tid = threadIdx.x;
  int v = (tid < NNODES / 1024) ? blksum[tid] : 0;
  sh[tid] = v; __syncthreads();
  for (int off = 1; off < 64; off <<= 1){
    int t = (tid >= off) ? sh[tid - off] : 0;
    __syncthreads(); sh[tid] += t; __syncthreads();
  }
  if (tid < NNODES / 1024) blksum[tid] = sh[tid] - v;
}
__global__ __launch_bounds__(1024) void scan3(int* __restrict__ offs, const int* __restrict__ blksum)
{
  int gid = blockIdx.x * 1024 + threadIdx.x;
  offs[gid] += blksum[blockIdx.x];
  if (gid == 0) offs[NNODES] = NEDGE;
}

// --------------------------- bucket scatter: sort by dst, pack (src<<4 | r)
__global__ void scatter_kernel(const int* __restrict__ ec, const int* __restrict__ rel,
                               const int* __restrict__ offs, int* __restrict__ cursor,
                               unsigned int* __restrict__ meta)
{
  int e = blockIdx.x * 256 + threadIdx.x;
  int s = ec[e];
  int d = ec[NEDGE + e];
  int r = rel[e];
  int p = offs[d] + atomicAdd(&cursor[d], 1);
  meta[p] = ((unsigned int)s << 4) | (unsigned int)r;
}

// -------- Wt[n][k] = stacked [basis;root]^T via LDS transpose, fp32 -> bf16
__global__ __launch_bounds__(256) void build_wt3(
    const float* __restrict__ basis,   // [1024,256] fp32 (= [4,256,256])
    const float* __restrict__ root,    // [256,256] fp32
    unsigned short* __restrict__ Wt)   // [256, KW] bf16
{
  __shared__ float tile[64][65];
  int t = threadIdx.x;
  int k0 = blockIdx.x * 64;            // 20 blocks
  int n0 = blockIdx.y * 64;            // 4 blocks
  int tn = t & 63, tk = t >> 6;
#pragma unroll
  for (int i = 0; i < 64; i += 4){
    int k = k0 + tk + i;
    float v = (k < KBASE) ? basis[(size_t)k * 256 + n0 + tn]
                          : root[(size_t)(k - KBASE) * 256 + n0 + tn];
    tile[tk + i][tn] = v;
  }
  __syncthreads();
#pragma unroll
  for (int i = 0; i < 64; i += 4){
    int n = n0 + tk + i;
    Wt[(size_t)n * KW + k0 + tn] = f2bf(tile[tn][tk + i]);
  }
}

// --------- fused comp-weighted segment sums; per-dst LDS weight table
__global__ __launch_bounds__(256) void agg5(
    const unsigned short* __restrict__ Xin,   // [N,256] bf16
    const int* __restrict__ offs,             // [N+1]
    const unsigned int* __restrict__ meta,    // packed src<<4|r
    const float* __restrict__ comp,           // [NREL*NBASES] fp32
    const int* __restrict__ cnt_rd,           // [NREL, N]
    unsigned short* __restrict__ z)           // [N, KBASE] bf16
{
  __shared__ __attribute__((aligned(16))) float wtab[4][40];  // [wave][r*4+b]
  int t = threadIdx.x;
  int wv = t >> 6, lane = t & 63;
  int d = blockIdx.x * 4 + wv;
  if (lane < 40){
    int r = lane >> 2, b = lane & 3;
    int cnt = cnt_rd[(r << 15) + d];
    wtab[wv][lane] = (cnt > 0) ? comp[r * NBASES + b] / (float)cnt : 0.0f;
  }
  __syncthreads();

  int col = lane * 4;
  const float4* wt4 = (const float4*)&wtab[wv][0];   // indexed by r

  float acc[NBASES][4] = {};
  int e0 = offs[d], e1 = offs[d + 1];
  int e = e0;
  for (; e + 3 < e1; e += 4){
    unsigned int m0 = meta[e], m1 = meta[e + 1], m2 = meta[e + 2], m3 = meta[e + 3];
    float4 w0 = wt4[m0 & 15u], w1 = wt4[m1 & 15u], w2 = wt4[m2 & 15u], w3 = wt4[m3 & 15u];
    ushort4 v0 = *(const ushort4*)(Xin + ((size_t)(m0 >> 4)) * 256 + col);
    ushort4 v1 = *(const ushort4*)(Xin + ((size_t)(m1 >> 4)) * 256 + col);
    ushort4 v2 = *(const ushort4*)(Xin + ((size_t)(m2 >> 4)) * 256 + col);
    ushort4 v3 = *(const ushort4*)(Xin + ((size_t)(m3 >> 4)) * 256 + col);
#pragma unroll
    for (int b = 0; b < NBASES; b++){
      float a0 = ((const float*)&w0)[b];
      float a1 = ((const float*)&w1)[b];
      float a2 = ((const float*)&w2)[b];
      float a3 = ((const float*)&w3)[b];
      acc[b][0] += a0 * bf2f(v0.x) + a1 * bf2f(v1.x) + a2 * bf2f(v2.x) + a3 * bf2f(v3.x);
      acc[b][1] += a0 * bf2f(v0.y) + a1 * bf2f(v1.y) + a2 * bf2f(v2.y) + a3 * bf2f(v3.y);
      acc[b][2] += a0 * bf2f(v0.z) + a1 * bf2f(v1.z) + a2 * bf2f(v2.z) + a3 * bf2f(v3.z);
      acc[b][3] += a0 * bf2f(v0.w) + a1 * bf2f(v1.w) + a2 * bf2f(v2.w) + a3 * bf2f(v3.w);
    }
  }
  for (; e < e1; ++e){
    unsigned int md = meta[e];
    float4 w = wt4[md & 15u];
    ushort4 v = *(const ushort4*)(Xin + ((size_t)(md >> 4)) * 256 + col);
#pragma unroll
    for (int b = 0; b < NBASES; b++){
      float a = ((const float*)&w)[b];
      acc[b][0] += a * bf2f(v.x); acc[b][1] += a * bf2f(v.y);
      acc[b][2] += a * bf2f(v.z); acc[b][3] += a * bf2f(v.w);
    }
  }
#pragma unroll
  for (int b = 0; b < NBASES; b++){
    ushort4 o;
    o.x = f2bf(acc[b][0]); o.y = f2bf(acc[b][1]);
    o.z = f2bf(acc[b][2]); o.w = f2bf(acc[b][3]);
    *(ushort4*)(z + (size_t)d * KBASE + b * 256 + col) = o;
  }
}

// ---- MFMA GEMM: Y[M,256] = [z | ext] @ Wt^T + bias  (tile 128m x 256n, K=1280)
// mode 1: outh = relu(v) bf16 ; mode 2: outf = v fp32
// LDS k-slot XOR swizzle: granule (row, kc) lives at slot (kc + (row>>1))&3
__global__ __launch_bounds__(256) void gemm5(
    const unsigned short* __restrict__ A0,   // z [M,KBASE]
    const unsigned short* __restrict__ A1,   // ext [M,256]
    const unsigned short* __restrict__ Wt,   // [256,KW]
    const float* __restrict__ bias,
    unsigned short* __restrict__ outh,
    float* __restrict__ outf,
    int mode)
{
  __shared__ __attribute__((aligned(16))) short As[128 * 32];   // 8 KB
  __shared__ __attribute__((aligned(16))) short Bs[256 * 32];   // 16 KB
  int tid  = threadIdx.x;
  int m0   = blockIdx.x * 128;
  int lane = tid & 63;
  int wn   = tid >> 6;               // wave = n-slice 0..3
  int lq = lane >> 4, lr = lane & 15;

  f32x4 zero = {0.f, 0.f, 0.f, 0.f};
  f32x4 acc[8][4];
#pragma unroll
  for (int i = 0; i < 8; i++)
#pragma unroll
    for (int j = 0; j < 4; j++) acc[i][j] = zero;

  for (int k0 = 0; k0 < KW; k0 += 32){
    __syncthreads();
    // A tile: 128 rows x 32 k = 512 granules
#pragma unroll
    for (int i = 0; i < 2; i++){
      int g   = tid + i * 256;
      int row = g >> 2;
      int kc  = ((g & 3) - (g >> 3)) & 3;
      const unsigned short* ga;
      if (k0 < KBASE) ga = A0 + (size_t)(m0 + row) * KBASE + k0 + kc * 8;
      else            ga = A1 + (size_t)(m0 + row) * 256 + (k0 - KBASE) + kc * 8;
      gll16(ga, As + g * 8);
    }
    // B tile: 256 rows x 32 k = 1024 granules
#pragma unroll
    for (int i = 0; i < 4; i++){
      int g   = tid + i * 256;
      int row = g >> 2;
      int kc  = ((g & 3) - (g >> 3)) & 3;
      gll16(Wt + (size_t)row * KW + k0 + kc * 8, Bs + g * 8);
    }
    __syncthreads();

    bf16x8 af[8], bfr[4];
#pragma unroll
    for (int i = 0; i < 8; i++){
      int row = i * 16 + lr;
      af[i] = *(const bf16x8*)(As + row * 32 + (((lq + (row >> 1)) & 3) * 8));
    }
#pragma unroll
    for (int j = 0; j < 4; j++){
      int row = wn * 64 + j * 16 + lr;
      bfr[j] = *(const bf16x8*)(Bs + row * 32 + (((lq + (row >> 1)) & 3) * 8));
    }
#pragma unroll
    for (int i = 0; i < 8; i++)
#pragma unroll
      for (int j = 0; j < 4; j++)
        acc[i][j] = __builtin_amdgcn_mfma_f32_16x16x32_bf16(af[i], bfr[j], acc[i][j], 0, 0, 0);
  }

  // C/D mapping: col=lane&15, row=(lane>>4)*4+reg  [m89/m91]
#pragma unroll
  for (int i = 0; i < 8; i++)
#pragma unroll
    for (int j = 0; j < 4; j++)
#pragma unroll
      for (int r = 0; r < 4; r++){
        int gm = m0 + i * 16 + lq * 4 + r;
        int gn = wn * 64 + j * 16 + lr;
        float v = acc[i][j][r] + bias[gn];
        size_t idx = (size_t)gm * 256 + gn;
        if (mode == 1) outh[idx] = f2bf(fmaxf(v, 0.f));
        else           outf[idx] = v;
      }
}

// ---------------------------------------------------------------------------
extern "C" void kernel_launch(void* const* d_in, const int* in_sizes, int n_in,
                              void* d_out, int out_size, void* d_ws, size_t ws_size,
                              hipStream_t stream)
{
  const float* x      = (const float*)d_in[0];
  const int*   ec     = (const int*)d_in[3];
  const int*   rel    = (const int*)d_in[4];
  const float* basis0 = (const float*)d_in[5];
  const float* comp0  = (const float*)d_in[6];
  const float* root0  = (const float*)d_in[7];
  const float* bias0  = (const float*)d_in[8];
  const float* basis1 = (const float*)d_in[9];
  const float* comp1  = (const float*)d_in[10];
  const float* root1  = (const float*)d_in[11];
  const float* bias1  = (const float*)d_in[12];

  char* p = (char*)d_ws;
  unsigned short* z  = (unsigned short*)p; p += (size_t)NNODES * KBASE * 2;   // 67.1 MB
  unsigned short* Xh = (unsigned short*)p; p += (size_t)NNODES * DIM * 2;     // 16.8
  unsigned short* h  = (unsigned short*)p; p += (size_t)NNODES * DIM * 2;     // 16.8
  unsigned short* Wt = (unsigned short*)p; p += (size_t)256 * KW * 2;         // 0.66
  unsigned int* meta = (unsigned int*)p; p += (size_t)NEDGE * 4;              // 2.1
  int* cnt_rd  = (int*)p;   p += (size_t)NREL * NNODES * 4;                   // 1.3
  int* cursor  = (int*)p;   p += (size_t)NNODES * 4;
  int* offs    = (int*)p;   p += (size_t)(NNODES + 1) * 4;
  int* blksum  = (int*)p;   p += 1024;

  // zero cnt_rd + cursor (contiguous)
  hipMemsetAsync(cnt_rd, 0, ((size_t)NREL * NNODES + (size_t)NNODES) * 4, stream);

  // ---- graph preprocessing (shared by both layers) ----
  hist_kernel   <<<NEDGE / 256, 256, 0, stream>>>(ec, rel, cnt_rd);
  scan1         <<<NNODES / 1024, 1024, 0, stream>>>(cnt_rd, offs, blksum);
  scan2         <<<1, 64, 0, stream>>>(blksum);
  scan3         <<<NNODES / 1024, 1024, 0, stream>>>(offs, blksum);
  scatter_kernel<<<NEDGE / 256, 256, 0, stream>>>(ec, rel, offs, cursor, meta);

  conv_kernel<<<(NNODES * DIM / 4) / 256, 256, 0, stream>>>(x, Xh);

  dim3 wgrid(KW / 64, 256 / 64);

  // ---- layer 0 ----
  build_wt3<<<wgrid, 256, 0, stream>>>(basis0, root0, Wt);
  agg5<<<NNODES / 4, 256, 0, stream>>>(Xh, offs, meta, comp0, cnt_rd, z);
  gemm5<<<NNODES / 128, 256, 0, stream>>>(z, Xh, Wt, bias0, h, nullptr, 1);

  // ---- layer 1 ----
  build_wt3<<<wgrid, 256, 0, stream>>>(basis1, root1, Wt);
  agg5<<<NNODES / 4, 256, 0, stream>>>(h, offs, meta, comp1, cnt_rd, z);
  gemm5<<<NNODES / 128, 256, 0, stream>>>(z, h, Wt, bias1, nullptr, (float*)d_out, 2);
}

// Round 7
// 330.053 us; speedup vs baseline: 1.1561x; 1.1561x over previous
//
#include <hip/hip_runtime.h>
#include <stdint.h>

#define NNODES 32768
#define NREL 10
#define NBASES 4
#define DIM 256
#define NEDGE 524288
#define KW 1280                 /* 4*256 basis + 256 root */
#define KBASE 1024              /* z width */

#define HB 2048                 /* hist blocks  */
#define CB 8192                 /* conv blocks  */
#define WB 80                   /* build_wt blocks per layer (20 k x 4 n) */

typedef __attribute__((ext_vector_type(8))) short bf16x8;
typedef __attribute__((ext_vector_type(4))) float f32x4;

__device__ __forceinline__ float bf2f(unsigned short u){
  union { unsigned int i; float f; } v; v.i = ((unsigned int)u) << 16; return v.f;
}
__device__ __forceinline__ unsigned short f2bf(float f){
  union { float f; unsigned int i; } v; v.f = f;
  unsigned int x = v.i;
  unsigned int r = (x + 0x7FFFu + ((x >> 16) & 1u)) >> 16;
  return (unsigned short)r;
}
__device__ __forceinline__ void gll16(const void* g, void* l){
  __builtin_amdgcn_global_load_lds((const __attribute__((address_space(1))) void*)g,
                                   (__attribute__((address_space(3))) void*)l, 16, 0, 0);
}

// ---- mega: fused independent prep  (hist | conv fp32->bf16 | build Wt0,Wt1)
__global__ __launch_bounds__(256) void mega_prep(
    const int* __restrict__ ec, const int* __restrict__ rel,
    int* __restrict__ cnt_rd,
    const float* __restrict__ x, unsigned short* __restrict__ Xh,
    const float* __restrict__ basis0, const float* __restrict__ root0,
    unsigned short* __restrict__ Wt0,
    const float* __restrict__ basis1, const float* __restrict__ root1,
    unsigned short* __restrict__ Wt1)
{
  __shared__ float tile[64][65];
  int bid = blockIdx.x;
  int t = threadIdx.x;
  if (bid < HB){
    // ---- histogram over (rel, dst)
    int e = bid * 256 + t;
    int d = ec[NEDGE + e];
    int r = rel[e];
    atomicAdd(&cnt_rd[(r << 15) + d], 1);
  } else if (bid < HB + CB){
    // ---- x fp32 -> bf16
    int i = (bid - HB) * 256 + t;
    float4 v = ((const float4*)x)[i];
    ushort4 o; o.x = f2bf(v.x); o.y = f2bf(v.y); o.z = f2bf(v.z); o.w = f2bf(v.w);
    ((ushort4*)Xh)[i] = o;
  } else {
    // ---- build Wt[n][k] = stacked [basis;root]^T via LDS transpose
    int b = bid - HB - CB;
    int layer = b / WB; b %= WB;
    const float* basis = layer ? basis1 : basis0;
    const float* root  = layer ? root1  : root0;
    unsigned short* Wt = layer ? Wt1    : Wt0;
    int k0 = (b % 20) * 64;
    int n0 = (b / 20) * 64;
    int tn = t & 63, tk = t >> 6;
#pragma unroll
    for (int i = 0; i < 64; i += 4){
      int k = k0 + tk + i;
      float v = (k < KBASE) ? basis[(size_t)k * 256 + n0 + tn]
                            : root[(size_t)(k - KBASE) * 256 + n0 + tn];
      tile[tk + i][tn] = v;
    }
    __syncthreads();
#pragma unroll
    for (int i = 0; i < 64; i += 4){
      int n = n0 + tk + i;
      Wt[(size_t)n * KW + k0 + tn] = f2bf(tile[tn][tk + i]);
    }
  }
}

// ---------------- 3-phase exclusive scan over deg (deg = sum_r cnt_rd[r,d])
__global__ __launch_bounds__(1024) void scan1(const int* __restrict__ cnt_rd,
                                              int* __restrict__ offs, int* __restrict__ blksum)
{
  __shared__ int sh[1024];
  int tid = threadIdx.x; int gid = blockIdx.x * 1024 + tid;
  int v = 0;
#pragma unroll
  for (int r = 0; r < NREL; r++) v += cnt_rd[(r << 15) + gid];
  sh[tid] = v; __syncthreads();
  for (int off = 1; off < 1024; off <<= 1){
    int t = (tid >= off) ? sh[tid - off] : 0;
    __syncthreads(); sh[tid] += t; __syncthreads();
  }
  offs[gid] = sh[tid] - v;
  if (tid == 1023) blksum[blockIdx.x] = sh[1023];
}
__global__ __launch_bounds__(64) void scan2(int* __restrict__ blksum)
{
  __shared__ int sh[64];
  int tid = threadIdx.x;
  int v = (tid < NNODES / 1024) ? blksum[tid] : 0;
  sh[tid] = v; __syncthreads();
  for (int off = 1; off < 64; off <<= 1){
    int t = (tid >= off) ? sh[tid - off] : 0;
    __syncthreads(); sh[tid] += t; __syncthreads();
  }
  if (tid < NNODES / 1024) blksum[tid] = sh[tid] - v;
}
__global__ __launch_bounds__(1024) void scan3(int* __restrict__ offs, const int* __restrict__ blksum)
{
  int gid = blockIdx.x * 1024 + threadIdx.x;
  offs[gid] += blksum[blockIdx.x];
  if (gid == 0) offs[NNODES] = NEDGE;
}

// --------------------------- bucket scatter: sort by dst, pack (src<<4 | r)
__global__ void scatter_kernel(const int* __restrict__ ec, const int* __restrict__ rel,
                               const int* __restrict__ offs, int* __restrict__ cursor,
                               unsigned int* __restrict__ meta)
{
  int e = blockIdx.x * 256 + threadIdx.x;
  int s = ec[e];
  int d = ec[NEDGE + e];
  int r = rel[e];
  int p = offs[d] + atomicAdd(&cursor[d], 1);
  meta[p] = ((unsigned int)s << 4) | (unsigned int)r;
}

// --------- fused comp-weighted segment sums; per-dst LDS weight table
__global__ __launch_bounds__(256) void agg5(
    const unsigned short* __restrict__ Xin,   // [N,256] bf16
    const int* __restrict__ offs,             // [N+1]
    const unsigned int* __restrict__ meta,    // packed src<<4|r
    const float* __restrict__ comp,           // [NREL*NBASES] fp32
    const int* __restrict__ cnt_rd,           // [NREL, N]
    unsigned short* __restrict__ z)           // [N, KBASE] bf16
{
  __shared__ __attribute__((aligned(16))) float wtab[4][40];  // [wave][r*4+b]
  int t = threadIdx.x;
  int wv = t >> 6, lane = t & 63;
  int d = blockIdx.x * 4 + wv;
  if (lane < 40){
    int r = lane >> 2, b = lane & 3;
    int cnt = cnt_rd[(r << 15) + d];
    wtab[wv][lane] = (cnt > 0) ? comp[r * NBASES + b] / (float)cnt : 0.0f;
  }
  __syncthreads();

  int col = lane * 4;
  const float4* wt4 = (const float4*)&wtab[wv][0];   // indexed by r

  float acc[NBASES][4] = {};
  int e0 = offs[d], e1 = offs[d + 1];
  int e = e0;
  for (; e + 3 < e1; e += 4){
    unsigned int m0 = meta[e], m1 = meta[e + 1], m2 = meta[e + 2], m3 = meta[e + 3];
    float4 w0 = wt4[m0 & 15u], w1 = wt4[m1 & 15u], w2 = wt4[m2 & 15u], w3 = wt4[m3 & 15u];
    ushort4 v0 = *(const ushort4*)(Xin + ((size_t)(m0 >> 4)) * 256 + col);
    ushort4 v1 = *(const ushort4*)(Xin + ((size_t)(m1 >> 4)) * 256 + col);
    ushort4 v2 = *(const ushort4*)(Xin + ((size_t)(m2 >> 4)) * 256 + col);
    ushort4 v3 = *(const ushort4*)(Xin + ((size_t)(m3 >> 4)) * 256 + col);
#pragma unroll
    for (int b = 0; b < NBASES; b++){
      float a0 = ((const float*)&w0)[b];
      float a1 = ((const float*)&w1)[b];
      float a2 = ((const float*)&w2)[b];
      float a3 = ((const float*)&w3)[b];
      acc[b][0] += a0 * bf2f(v0.x) + a1 * bf2f(v1.x) + a2 * bf2f(v2.x) + a3 * bf2f(v3.x);
      acc[b][1] += a0 * bf2f(v0.y) + a1 * bf2f(v1.y) + a2 * bf2f(v2.y) + a3 * bf2f(v3.y);
      acc[b][2] += a0 * bf2f(v0.z) + a1 * bf2f(v1.z) + a2 * bf2f(v2.z) + a3 * bf2f(v3.z);
      acc[b][3] += a0 * bf2f(v0.w) + a1 * bf2f(v1.w) + a2 * bf2f(v2.w) + a3 * bf2f(v3.w);
    }
  }
  for (; e < e1; ++e){
    unsigned int md = meta[e];
    float4 w = wt4[md & 15u];
    ushort4 v = *(const ushort4*)(Xin + ((size_t)(md >> 4)) * 256 + col);
#pragma unroll
    for (int b = 0; b < NBASES; b++){
      float a = ((const float*)&w)[b];
      acc[b][0] += a * bf2f(v.x); acc[b][1] += a * bf2f(v.y);
      acc[b][2] += a * bf2f(v.z); acc[b][3] += a * bf2f(v.w);
    }
  }
#pragma unroll
  for (int b = 0; b < NBASES; b++){
    ushort4 o;
    o.x = f2bf(acc[b][0]); o.y = f2bf(acc[b][1]);
    o.z = f2bf(acc[b][2]); o.w = f2bf(acc[b][3]);
    *(ushort4*)(z + (size_t)d * KBASE + b * 256 + col) = o;
  }
}

// ---- MFMA GEMM: Y[M,256] = [z | ext] @ Wt^T + bias  (tile 64m x 256n, K=1280)
// mode 1: outh = relu(v) bf16 ; mode 2: outf = v fp32
// LDS k-slot XOR swizzle: granule (row, kc) lives at slot (kc + (row>>1))&3
__global__ __launch_bounds__(256) void gemm4(
    const unsigned short* __restrict__ A0,   // z [M,KBASE]
    const unsigned short* __restrict__ A1,   // ext [M,256]
    const unsigned short* __restrict__ Wt,   // [256,KW]
    const float* __restrict__ bias,
    unsigned short* __restrict__ outh,
    float* __restrict__ outf,
    int mode)
{
  __shared__ __attribute__((aligned(16))) short As[64 * 32];    // 4 KB
  __shared__ __attribute__((aligned(16))) short Bs[256 * 32];   // 16 KB
  int tid  = threadIdx.x;
  int m0   = blockIdx.x * 64;
  int lane = tid & 63;
  int wn   = tid >> 6;               // wave = n-slice 0..3
  int lq = lane >> 4, lr = lane & 15;

  f32x4 zero = {0.f, 0.f, 0.f, 0.f};
  f32x4 acc[4][4];
#pragma unroll
  for (int i = 0; i < 4; i++)
#pragma unroll
    for (int j = 0; j < 4; j++) acc[i][j] = zero;

  // A staging source params (row = tid>>2, kc = inverse swizzle)
  int arow = tid >> 2;
  int akc  = ((tid & 3) - (tid >> 3)) & 3;

  for (int k0 = 0; k0 < KW; k0 += 32){
    __syncthreads();
    {
      const unsigned short* ga;
      if (k0 < KBASE) ga = A0 + (size_t)(m0 + arow) * KBASE + k0 + akc * 8;
      else            ga = A1 + (size_t)(m0 + arow) * 256 + (k0 - KBASE) + akc * 8;
      gll16(ga, As + tid * 8);
    }
#pragma unroll
    for (int i = 0; i < 4; i++){
      int gb  = tid + i * 256;             // 0..1023 B granules
      int row = gb >> 2;
      int kc  = ((gb & 3) - (gb >> 3)) & 3;
      gll16(Wt + (size_t)row * KW + k0 + kc * 8, Bs + gb * 8);
    }
    __syncthreads();

    bf16x8 af[4], bfr[4];
#pragma unroll
    for (int i = 0; i < 4; i++){
      int row = i * 16 + lr;
      af[i] = *(const bf16x8*)(As + row * 32 + (((lq + (row >> 1)) & 3) * 8));
    }
#pragma unroll
    for (int j = 0; j < 4; j++){
      int row = wn * 64 + j * 16 + lr;
      bfr[j] = *(const bf16x8*)(Bs + row * 32 + (((lq + (row >> 1)) & 3) * 8));
    }
#pragma unroll
    for (int i = 0; i < 4; i++)
#pragma unroll
      for (int j = 0; j < 4; j++)
        acc[i][j] = __builtin_amdgcn_mfma_f32_16x16x32_bf16(af[i], bfr[j], acc[i][j], 0, 0, 0);
  }

  // C/D mapping: col=lane&15, row=(lane>>4)*4+reg  [m89/m91]
#pragma unroll
  for (int i = 0; i < 4; i++)
#pragma unroll
    for (int j = 0; j < 4; j++)
#pragma unroll
      for (int r = 0; r < 4; r++){
        int gm = m0 + i * 16 + lq * 4 + r;
        int gn = wn * 64 + j * 16 + lr;
        float v = acc[i][j][r] + bias[gn];
        size_t idx = (size_t)gm * 256 + gn;
        if (mode == 1) outh[idx] = f2bf(fmaxf(v, 0.f));
        else           outf[idx] = v;
      }
}

// ---------------------------------------------------------------------------
extern "C" void kernel_launch(void* const* d_in, const int* in_sizes, int n_in,
                              void* d_out, int out_size, void* d_ws, size_t ws_size,
                              hipStream_t stream)
{
  const float* x      = (const float*)d_in[0];
  const int*   ec     = (const int*)d_in[3];
  const int*   rel    = (const int*)d_in[4];
  const float* basis0 = (const float*)d_in[5];
  const float* comp0  = (const float*)d_in[6];
  const float* root0  = (const float*)d_in[7];
  const float* bias0  = (const float*)d_in[8];
  const float* basis1 = (const float*)d_in[9];
  const float* comp1  = (const float*)d_in[10];
  const float* root1  = (const float*)d_in[11];
  const float* bias1  = (const float*)d_in[12];

  char* p = (char*)d_ws;
  unsigned short* z   = (unsigned short*)p; p += (size_t)NNODES * KBASE * 2;  // 67.1 MB
  unsigned short* Xh  = (unsigned short*)p; p += (size_t)NNODES * DIM * 2;    // 16.8
  unsigned short* h   = (unsigned short*)p; p += (size_t)NNODES * DIM * 2;    // 16.8
  unsigned short* Wt0 = (unsigned short*)p; p += (size_t)256 * KW * 2;        // 0.66
  unsigned short* Wt1 = (unsigned short*)p; p += (size_t)256 * KW * 2;        // 0.66
  unsigned int* meta  = (unsigned int*)p;   p += (size_t)NEDGE * 4;           // 2.1
  int* cnt_rd  = (int*)p;   p += (size_t)NREL * NNODES * 4;                   // 1.3
  int* cursor  = (int*)p;   p += (size_t)NNODES * 4;
  int* offs    = (int*)p;   p += (size_t)(NNODES + 1) * 4;
  int* blksum  = (int*)p;   p += 1024;

  // zero cnt_rd + cursor (contiguous)
  hipMemsetAsync(cnt_rd, 0, ((size_t)NREL * NNODES + (size_t)NNODES) * 4, stream);

  // ---- fused prep: hist | conv | build Wt0 | build Wt1 ----
  mega_prep<<<HB + CB + 2 * WB, 256, 0, stream>>>(
      ec, rel, cnt_rd, x, Xh, basis0, root0, Wt0, basis1, root1, Wt1);

  scan1<<<NNODES / 1024, 1024, 0, stream>>>(cnt_rd, offs, blksum);
  scan2<<<1, 64, 0, stream>>>(blksum);
  scan3<<<NNODES / 1024, 1024, 0, stream>>>(offs, blksum);
  scatter_kernel<<<NEDGE / 256, 256, 0, stream>>>(ec, rel, offs, cursor, meta);

  // ---- layer 0 ----
  agg5<<<NNODES / 4, 256, 0, stream>>>(Xh, offs, meta, comp0, cnt_rd, z);
  gemm4<<<NNODES / 64, 256, 0, stream>>>(z, Xh, Wt0, bias0, h, nullptr, 1);

  // ---- layer 1 ----
  agg5<<<NNODES / 4, 256, 0, stream>>>(h, offs, meta, comp1, cnt_rd, z);
  gemm4<<<NNODES / 64, 256, 0, stream>>>(z, h, Wt1, bias1, nullptr, (float*)d_out, 2);
}